// Round 3
// baseline (882.873 us; speedup 1.0000x reference)
//
#include <hip/hip_runtime.h>
#include <hip/hip_bf16.h>

#define HH 448
#define WW 512
#define CC 128
#define CHW (HH*WW)          // channel stride in x_in = 229376
#define NPIX (HH*WW)         // 229376 pixels
#define WCH 128              // w-chunk per stage-1 block
#define LD 132               // padded LDS row stride (floats)

typedef unsigned short u16;
typedef __attribute__((ext_vector_type(8))) u16 ushort8v;

__device__ __forceinline__ float lrelu(float v) { return v >= 0.f ? v : 0.01f * v; }

__device__ __forceinline__ u16 f2bf(float v) {
    __hip_bfloat16 b = __float2bfloat16(v);
    union { __hip_bfloat16 h; u16 u; } cv; cv.h = b;
    return cv.u;
}

__device__ __forceinline__ float bf2f(u16 u) {
    union { unsigned int i; float f; } cv; cv.i = ((unsigned int)u) << 16;
    return cv.f;
}

// One GEMM phase: out[o][w] = sum_k Wt[o][k] * src[k][w], K=128 streamed in 4 panels of 32.
// Weights wsrc: fp32 [O][128] row-major at its h offset. Result left in acc (bias NOT applied).
// EXTRA: also accumulate row o=128 (for O=129) into a128 on threads tid<128 (w = tid).
template<bool EXTRA>
__device__ __forceinline__ void gemm_phase(
    const float* __restrict__ wsrc, const float* __restrict__ bsrc, int O,
    const float* __restrict__ sbuf, float* __restrict__ wtb, float* __restrict__ biasb,
    float (&acc)[8][8], float& a128, int tid, int o0, int w0)
{
#pragma unroll
    for (int i = 0; i < 8; ++i)
#pragma unroll
        for (int j = 0; j < 8; ++j) acc[i][j] = 0.f;
    a128 = 0.f;

    for (int pan = 0; pan < 4; ++pan) {
        __syncthreads();   // wt buffer free; also covers previous-phase epilogue reads
        // ---- load weight panel transposed: wtb[kk][o] = wsrc[o*128 + pan*32+kk] ----
#pragma unroll
        for (int it = 0; it < 4; ++it) {
            int slot = it * 256 + tid;
            int o  = slot & 127;
            int kq = slot >> 7;            // 0..7 (quad of k within panel)
            const float4 wv = *(const float4*)(wsrc + o * 128 + pan * 32 + kq * 4);
            wtb[(kq * 4 + 0) * LD + o] = wv.x;
            wtb[(kq * 4 + 1) * LD + o] = wv.y;
            wtb[(kq * 4 + 2) * LD + o] = wv.z;
            wtb[(kq * 4 + 3) * LD + o] = wv.w;
        }
        if (EXTRA) {
            if (tid < 32) wtb[tid * LD + 128] = wsrc[128 * 128 + pan * 32 + tid];
        }
        if (pan == 0 && tid < O) biasb[tid] = bsrc[tid];
        __syncthreads();

        // ---- compute 32 k-steps ----
#pragma unroll 4
        for (int kk = 0; kk < 32; ++kk) {
            const int kg = pan * 32 + kk;
            const float4 xa = *(const float4*)(sbuf + kg * LD + w0);
            const float4 xb = *(const float4*)(sbuf + kg * LD + w0 + 4);
            const float4 wa = *(const float4*)(wtb + kk * LD + o0);
            const float4 wb = *(const float4*)(wtb + kk * LD + o0 + 4);
            const float xv[8] = {xa.x, xa.y, xa.z, xa.w, xb.x, xb.y, xb.z, xb.w};
            const float wv[8] = {wa.x, wa.y, wa.z, wa.w, wb.x, wb.y, wb.z, wb.w};
#pragma unroll
            for (int i = 0; i < 8; ++i)
#pragma unroll
                for (int j = 0; j < 8; ++j)
                    acc[i][j] = fmaf(wv[i], xv[j], acc[i][j]);
        }
        if (EXTRA && tid < 128) {
#pragma unroll 8
            for (int kk = 0; kk < 32; ++kk)
                a128 = fmaf(wtb[kk * LD + 128], sbuf[(pan * 32 + kk) * LD + tid], a128);
        }
    }
}

__global__ __launch_bounds__(256, 1) void stage1_kernel(
    const float* __restrict__ x_in,
    const float* __restrict__ w_cl1, const float* __restrict__ b_cl1,
    const float* __restrict__ w_cl2, const float* __restrict__ b_cl2,
    const float* __restrict__ w_cl3, const float* __restrict__ b_cl3,
    const float* __restrict__ w_reg1, const float* __restrict__ b_reg1,
    u16* __restrict__ xr_ws, int* __restrict__ inds_ws, float* __restrict__ out)
{
    __shared__ float xs[128 * LD];      // 67584 B : holds x, later t2
    __shared__ float ts[128 * LD];      // 67584 B : holds t1
    __shared__ float wtb[32 * LD];      // 16896 B : weight panel / argmax scratch
    __shared__ float biasb[LD];

    const int tid = threadIdx.x;
    const int b = blockIdx.x;
    // swizzle: all 4 chunks of an h on the same XCD, temporally adjacent
    const int h     = (b >> 5) * 8 + (b & 7);
    const int chunk = (b >> 3) & 3;
    const int wbase = chunk * WCH;

    const int og = tid >> 4, wg = tid & 15;
    const int o0 = og * 8,  w0 = wg * 8;

    // ---- load x chunk: xs[c][w] = x_in[c][h][wbase+w] ----
    {
        const float* xg = x_in + h * WW + wbase;
#pragma unroll
        for (int it = 0; it < 16; ++it) {
            int slot = it * 256 + tid;       // 4096 float4 slots: c = slot>>5, w4 = slot&31
            int c = slot >> 5, w4 = slot & 31;
            float4 v = *(const float4*)(xg + (size_t)c * CHW + w4 * 4);
            *(float4*)(xs + c * LD + w4 * 4) = v;
        }
    }
    // (gemm_phase's first __syncthreads covers the x load)

    float acc[8][8]; float a128;

    // ---- phase 1: t1 = lrelu(W1 @ x + b1) ----
    gemm_phase<false>(w_cl1 + (size_t)h * 16384, b_cl1 + h * 128, 128, xs, wtb, biasb, acc, a128, tid, o0, w0);
#pragma unroll
    for (int i = 0; i < 8; ++i) {
        float bo = biasb[o0 + i];
#pragma unroll
        for (int j = 0; j < 8; ++j)
            ts[(o0 + i) * LD + w0 + j] = lrelu(acc[i][j] + bo);
    }

    // ---- phase 2: x_r = lrelu(Wr @ x + br)  -> bf16 to workspace ----
    gemm_phase<false>(w_reg1 + (size_t)h * 16384, b_reg1 + h * 128, 128, xs, wtb, biasb, acc, a128, tid, o0, w0);
    {
        const int pbase = h * WW + wbase + w0;
#pragma unroll
        for (int j = 0; j < 8; ++j) {
            ushort8v pk;
#pragma unroll
            for (int i = 0; i < 8; ++i)
                pk[i] = f2bf(lrelu(acc[i][j] + biasb[o0 + i]));
            *(ushort8v*)(xr_ws + (size_t)(pbase + j) * 128 + o0) = pk;
        }
    }

    // ---- phase 3: t2 = lrelu(W2 @ t1 + b2) -> overwrite xs ----
    gemm_phase<false>(w_cl2 + (size_t)h * 16384, b_cl2 + h * 128, 128, ts, wtb, biasb, acc, a128, tid, o0, w0);
#pragma unroll
    for (int i = 0; i < 8; ++i) {
        float bo = biasb[o0 + i];
#pragma unroll
        for (int j = 0; j < 8; ++j)
            xs[(o0 + i) * LD + w0 + j] = lrelu(acc[i][j] + bo);
    }

    // ---- phase 4: cl = W3 @ t2 + b3 (O=129), argmax + mask ----
    gemm_phase<true>(w_cl3 + (size_t)h * 16512, b_cl3 + h * 129, 129, xs, wtb, biasb, acc, a128, tid, o0, w0);

    __syncthreads();   // wt buffer -> argmax scratch
    float* sval = wtb;
    int*   sidx = (int*)(wtb + 2048);
#pragma unroll
    for (int j = 0; j < 8; ++j) {
        float bv = -3.4e38f; int bi = 0;
#pragma unroll
        for (int i = 0; i < 8; ++i) {
            float v = acc[i][j] + biasb[o0 + i];
            if (v > bv) { bv = v; bi = o0 + i; }   // strict > => first-max (numpy rule)
        }
        sval[og * 128 + (w0 + j)] = bv;
        sidx[og * 128 + (w0 + j)] = bi;
    }
    __syncthreads();
    if (tid < 128) {
        const int w = tid;
        float bv = sval[w]; int bi = sidx[w];
#pragma unroll
        for (int g = 1; g < 16; ++g) {
            float v = sval[g * 128 + w];
            if (v > bv) { bv = v; bi = sidx[g * 128 + w]; }
        }
        inds_ws[h * WW + wbase + w] = bi;
        out[NPIX + h * WW + wbase + w] = lrelu(a128 + biasb[128]);  // mask output (fp32)
    }
}

__global__ __launch_bounds__(256, 4) void stage2_kernel(
    const u16* __restrict__ xr_ws, const int* __restrict__ inds_ws,
    const float* __restrict__ w2g, const float* __restrict__ b2g,
    const float* __restrict__ w3g, const float* __restrict__ b3g,
    float* __restrict__ out)
{
    const int lane = threadIdx.x & 63;
    const int p = blockIdx.x * 4 + (threadIdx.x >> 6);   // output pixel, p = h*512 + w
    const int h = p >> 9, w = p & 511;
    // reference's index scramble: n = w*448 + h interpreted h-major for the weight index
    const int n  = w * HH + h;
    const int hp = n >> 9, wp = n & 511;
    const int idx = inds_ws[(hp << 9) + wp] + (hp << 7);

    const int c0 = lane << 1;
    const u16* rp = xr_ws + (size_t)p * 128 + c0;
    const float r0 = bf2f(rp[0]), r1 = bf2f(rp[1]);

    // w2[idx] is [c][o] fp32, c-stride 4: rows c0, c0+1 -> two float4
    const float* wrow = w2g + (size_t)idx * 512;
    const float4 wa = *(const float4*)(wrow + (c0 << 2));
    const float4 wb = *(const float4*)(wrow + (c0 << 2) + 4);

    float s0 = r0 * wa.x + r1 * wb.x;
    float s1 = r0 * wa.y + r1 * wb.y;
    float s2 = r0 * wa.z + r1 * wb.z;
    float s3 = r0 * wa.w + r1 * wb.w;
#pragma unroll
    for (int m = 1; m < 64; m <<= 1) {
        s0 += __shfl_xor(s0, m, 64);
        s1 += __shfl_xor(s1, m, 64);
        s2 += __shfl_xor(s2, m, 64);
        s3 += __shfl_xor(s3, m, 64);
    }
    const float4 b2v = *(const float4*)(b2g + (idx << 2));
    const float4 w3v = *(const float4*)(w3g + (idx << 2));
    float rr = b3g[idx];
    rr += lrelu(s0 + b2v.x) * w3v.x;
    rr += lrelu(s1 + b2v.y) * w3v.y;
    rr += lrelu(s2 + b2v.z) * w3v.z;
    rr += lrelu(s3 + b2v.w) * w3v.w;
    if (lane == 0) {
        const float ind_local = (float)inds_ws[p];
        out[p] = (ind_local + rr) * 0.0078125f;
    }
}

extern "C" void kernel_launch(void* const* d_in, const int* in_sizes, int n_in,
                              void* d_out, int out_size, void* d_ws, size_t ws_size,
                              hipStream_t stream)
{
    const float* x_in   = (const float*)d_in[0];
    const float* w_cl1  = (const float*)d_in[1];
    const float* b_cl1  = (const float*)d_in[2];
    const float* w_cl2  = (const float*)d_in[3];
    const float* b_cl2  = (const float*)d_in[4];
    const float* w_cl3  = (const float*)d_in[5];
    const float* b_cl3  = (const float*)d_in[6];
    const float* w_reg1 = (const float*)d_in[7];
    const float* b_reg1 = (const float*)d_in[8];
    const float* w2     = (const float*)d_in[9];
    const float* b2     = (const float*)d_in[10];
    const float* w3     = (const float*)d_in[11];
    const float* b3     = (const float*)d_in[12];

    float* out = (float*)d_out;
    u16* xr_ws = (u16*)d_ws;                                        // 229376*128 bf16 = 58,720,256 B
    int* inds  = (int*)((char*)d_ws + (size_t)NPIX * 128 * 2);      // + 917,504 B

    stage1_kernel<<<dim3(448 * 4), dim3(256), 0, stream>>>(
        x_in, w_cl1, b_cl1, w_cl2, b_cl2, w_cl3, b_cl3, w_reg1, b_reg1,
        xr_ws, inds, out);

    stage2_kernel<<<dim3(NPIX / 4), dim3(256), 0, stream>>>(
        xr_ws, inds, w2, b2, w3, b3, out);
}

// Round 4
// 708.576 us; speedup vs baseline: 1.2460x; 1.2460x over previous
//
#include <hip/hip_runtime.h>
#include <hip/hip_bf16.h>

#define HH 448
#define WW 512
#define CHW (HH*WW)          // channel stride in x_in = 229376
#define NPIX (HH*WW)         // 229376 pixels
#define WCH 128              // w-chunk per stage-1 block
#define LDW 140              // xs physical row stride (words), swizzled layout
#define WLD 132              // wtb row stride (words)

typedef unsigned short u16;
typedef __attribute__((ext_vector_type(8))) u16 ushort8v;

__device__ __forceinline__ float lrelu(float v) { return v >= 0.f ? v : 0.01f * v; }

__device__ __forceinline__ u16 f2bf(float v) {
    __hip_bfloat16 b = __float2bfloat16(v);
    union { __hip_bfloat16 h; u16 u; } cv; cv.h = b;
    return cv.u;
}

__device__ __forceinline__ float bf2f(u16 u) {
    union { unsigned int i; float f; } cv; cv.i = ((unsigned int)u) << 16;
    return cv.f;
}

// swizzled base word of 8-float group g (g = w>>3): spreads the 16 groups over
// 8 bank-quads -> 2-way aliasing (free) instead of 4-way. Max offset 132+7 -> LDW=140.
__device__ __forceinline__ int swz8(int g) { return g * 8 + ((g >> 2) << 2); }

// One GEMM phase: acc[o][w] += sum_k W[o][k] * sbuf[k][w], K=128 in 8 panels of 16.
// sbuf rows use the swizzled layout (stride LDW). Result left in acc (bias NOT applied).
// EXTRA: also accumulate row o=128 (O=129) into a128 on threads tid<128 (col = tid).
template<bool EXTRA>
__device__ __forceinline__ void gemm_phase(
    const float* __restrict__ wsrc, const float* __restrict__ bsrc, int O,
    const float* __restrict__ sbuf, float* __restrict__ wtb, float* __restrict__ biasb,
    float (&acc)[8][8], float& a128, int tid, int o0, int xoff, int swtid)
{
#pragma unroll
    for (int i = 0; i < 8; ++i)
#pragma unroll
        for (int j = 0; j < 8; ++j) acc[i][j] = 0.f;
    a128 = 0.f;

    for (int pan = 0; pan < 8; ++pan) {
        __syncthreads();   // wtb free (prev panel consumed / prev phase done)
        // ---- stage weight panel transposed: wtb[kk][o] = wsrc[o*128 + pan*16+kk] ----
#pragma unroll
        for (int it = 0; it < 2; ++it) {
            int slot = it * 256 + tid;      // 512 slots
            int kq = slot & 3;              // which float4 of the 16-k panel
            int o  = slot >> 2;             // 0..127
            const float4 wv = *(const float4*)(wsrc + o * 128 + pan * 16 + kq * 4);
            wtb[(kq * 4 + 0) * WLD + o] = wv.x;
            wtb[(kq * 4 + 1) * WLD + o] = wv.y;
            wtb[(kq * 4 + 2) * WLD + o] = wv.z;
            wtb[(kq * 4 + 3) * WLD + o] = wv.w;
        }
        if (EXTRA && tid < 4) {
            const float4 wv = *(const float4*)(wsrc + 128 * 128 + pan * 16 + tid * 4);
            wtb[(tid * 4 + 0) * WLD + 128] = wv.x;
            wtb[(tid * 4 + 1) * WLD + 128] = wv.y;
            wtb[(tid * 4 + 2) * WLD + 128] = wv.z;
            wtb[(tid * 4 + 3) * WLD + 128] = wv.w;
        }
        if (pan == 0 && tid < O) biasb[tid] = bsrc[tid];
        __syncthreads();

        // ---- 16 k-steps ----
#pragma unroll 4
        for (int kk = 0; kk < 16; ++kk) {
            const int kg = pan * 16 + kk;
            const float4 xa = *(const float4*)(sbuf + kg * LDW + xoff);
            const float4 xb = *(const float4*)(sbuf + kg * LDW + xoff + 4);
            const float4 wa = *(const float4*)(wtb + kk * WLD + o0);
            const float4 wb = *(const float4*)(wtb + kk * WLD + o0 + 4);
            const float xv[8] = {xa.x, xa.y, xa.z, xa.w, xb.x, xb.y, xb.z, xb.w};
            const float wv[8] = {wa.x, wa.y, wa.z, wa.w, wb.x, wb.y, wb.z, wb.w};
#pragma unroll
            for (int i = 0; i < 8; ++i)
#pragma unroll
                for (int j = 0; j < 8; ++j)
                    acc[i][j] = fmaf(wv[i], xv[j], acc[i][j]);
        }
        if (EXTRA && tid < 128) {
#pragma unroll 4
            for (int kk = 0; kk < 16; ++kk)
                a128 = fmaf(wtb[kk * WLD + 128], sbuf[(pan * 16 + kk) * LDW + swtid], a128);
        }
    }
}

__global__ __launch_bounds__(256, 2) void stage1_kernel(
    const float* __restrict__ x_in,
    const float* __restrict__ w_cl1, const float* __restrict__ b_cl1,
    const float* __restrict__ w_cl2, const float* __restrict__ b_cl2,
    const float* __restrict__ w_cl3, const float* __restrict__ b_cl3,
    const float* __restrict__ w_reg1, const float* __restrict__ b_reg1,
    u16* __restrict__ xr_ws, int* __restrict__ inds_ws, float* __restrict__ out)
{
    __shared__ float xs[128 * LDW];     // 71,680 B : x -> t1 -> t2 (single live buffer)
    __shared__ float wtb[16 * WLD];     //  8,448 B : weight panel / later argmax scratch in xs
    __shared__ float biasb[WLD];        //    528 B
    // total 80,656 B -> 2 blocks/CU (8 waves/CU)

    const int tid = threadIdx.x;
    const int b = blockIdx.x;
    // swizzle: all 4 chunks of an h temporally adjacent (L2 weight reuse)
    const int h     = (b >> 5) * 8 + (b & 7);
    const int chunk = (b >> 3) & 3;
    const int wbase = chunk * WCH;

    const int og = tid >> 4, wg = tid & 15;
    const int o0 = og * 8,  w0 = wg * 8;
    const int xoff  = swz8(wg);                                   // compute-loop x offset
    const int swtid = swz8(tid >> 3) + (tid & 7);                 // scalar swizzled col=tid

    // ---- load x chunk: xs[c][w] = x_in[c][h][wbase+w] (swizzled store) ----
    {
        const float* xg = x_in + h * WW + wbase;
#pragma unroll
        for (int it = 0; it < 16; ++it) {
            int slot = it * 256 + tid;       // 4096 float4 slots
            int c = slot >> 5, w4 = slot & 31;
            float4 v = *(const float4*)(xg + (size_t)c * CHW + w4 * 4);
            *(float4*)(xs + c * LDW + swz8(w4 >> 1) + (w4 & 1) * 4) = v;
        }
    }
    // (gemm_phase's first __syncthreads covers the x load)

    float acc[8][8]; float a128;

    // ---- phase A: x_r = lrelu(Wr @ x + br) -> bf16 workspace, n-ordered ----
    gemm_phase<false>(w_reg1 + (size_t)h * 16384, b_reg1 + h * 128, 128, xs, wtb, biasb, acc, a128, tid, o0, xoff, swtid);
    {
#pragma unroll
        for (int j = 0; j < 8; ++j) {
            const int n = (wbase + w0 + j) * HH + h;   // n = w*448 + h
            ushort8v pk;
#pragma unroll
            for (int i = 0; i < 8; ++i)
                pk[i] = f2bf(lrelu(acc[i][j] + biasb[o0 + i]));
            *(ushort8v*)(xr_ws + (size_t)n * 128 + o0) = pk;
        }
    }

    // ---- phase B: t1 = lrelu(W1 @ x + b1) -> overwrite xs (x dead) ----
    gemm_phase<false>(w_cl1 + (size_t)h * 16384, b_cl1 + h * 128, 128, xs, wtb, biasb, acc, a128, tid, o0, xoff, swtid);
    __syncthreads();
#pragma unroll
    for (int i = 0; i < 8; ++i) {
        float bo = biasb[o0 + i];
        *(float4*)(xs + (o0 + i) * LDW + xoff) =
            make_float4(lrelu(acc[i][0] + bo), lrelu(acc[i][1] + bo), lrelu(acc[i][2] + bo), lrelu(acc[i][3] + bo));
        *(float4*)(xs + (o0 + i) * LDW + xoff + 4) =
            make_float4(lrelu(acc[i][4] + bo), lrelu(acc[i][5] + bo), lrelu(acc[i][6] + bo), lrelu(acc[i][7] + bo));
    }

    // ---- phase C: t2 = lrelu(W2 @ t1 + b2) -> overwrite xs ----
    gemm_phase<false>(w_cl2 + (size_t)h * 16384, b_cl2 + h * 128, 128, xs, wtb, biasb, acc, a128, tid, o0, xoff, swtid);
    __syncthreads();
#pragma unroll
    for (int i = 0; i < 8; ++i) {
        float bo = biasb[o0 + i];
        *(float4*)(xs + (o0 + i) * LDW + xoff) =
            make_float4(lrelu(acc[i][0] + bo), lrelu(acc[i][1] + bo), lrelu(acc[i][2] + bo), lrelu(acc[i][3] + bo));
        *(float4*)(xs + (o0 + i) * LDW + xoff + 4) =
            make_float4(lrelu(acc[i][4] + bo), lrelu(acc[i][5] + bo), lrelu(acc[i][6] + bo), lrelu(acc[i][7] + bo));
    }

    // ---- phase D: cl = W3 @ t2 + b3 (O=129), argmax + mask ----
    gemm_phase<true>(w_cl3 + (size_t)h * 16512, b_cl3 + h * 129, 129, xs, wtb, biasb, acc, a128, tid, o0, xoff, swtid);

    __syncthreads();   // xs compute reads done -> reuse as argmax scratch
    float* sval = xs;
    int*   sidx = (int*)(xs + 2048);
#pragma unroll
    for (int j = 0; j < 8; ++j) {
        float bv = -3.4e38f; int bi = 0;
#pragma unroll
        for (int i = 0; i < 8; ++i) {
            float v = acc[i][j] + biasb[o0 + i];
            if (v > bv) { bv = v; bi = o0 + i; }   // strict > => first-max (numpy rule)
        }
        sval[og * 128 + (w0 + j)] = bv;
        sidx[og * 128 + (w0 + j)] = bi;
    }
    __syncthreads();
    if (tid < 128) {
        const int w = tid;
        float bv = sval[w]; int bi = sidx[w];
#pragma unroll
        for (int g = 1; g < 16; ++g) {
            float v = sval[g * 128 + w];
            if (v > bv) { bv = v; bi = sidx[g * 128 + w]; }
        }
        inds_ws[h * WW + wbase + w] = bi;                       // p-ordered
        out[NPIX + h * WW + wbase + w] = lrelu(a128 + biasb[128]);  // mask (fp32)
    }
}

__global__ __launch_bounds__(256, 4) void stage2_kernel(
    const u16* __restrict__ xr_ws, const int* __restrict__ inds_ws,
    const float* __restrict__ w2g, const float* __restrict__ b2g,
    const float* __restrict__ w3g, const float* __restrict__ b3g,
    float* __restrict__ out)
{
    const int lane = threadIdx.x & 63;
    const int n = blockIdx.x * 4 + (threadIdx.x >> 6);   // n-ordered: sequential gathers
    const unsigned un = (unsigned)n;
    const int h = un % 448u, w = un / 448u;              // output pixel p = h*512 + w
    // weight index: inds_r[n] = inds_flat[n] + (n>>9)*128  (inds_flat is p-ordered)
    const int idx = inds_ws[n] + ((n >> 9) << 7);

    const int c0 = lane << 1;
    const u16* rp = xr_ws + (size_t)n * 128 + c0;        // xr stored n-ordered
    const float r0 = bf2f(rp[0]), r1 = bf2f(rp[1]);

    // w2[idx] is [c][o] fp32, o-stride 1, c-stride 4: rows c0, c0+1 -> two float4
    const float* wrow = w2g + (size_t)idx * 512;
    const float4 wa = *(const float4*)(wrow + (c0 << 2));
    const float4 wb = *(const float4*)(wrow + (c0 << 2) + 4);

    float s0 = r0 * wa.x + r1 * wb.x;
    float s1 = r0 * wa.y + r1 * wb.y;
    float s2 = r0 * wa.z + r1 * wb.z;
    float s3 = r0 * wa.w + r1 * wb.w;
#pragma unroll
    for (int m = 1; m < 64; m <<= 1) {
        s0 += __shfl_xor(s0, m, 64);
        s1 += __shfl_xor(s1, m, 64);
        s2 += __shfl_xor(s2, m, 64);
        s3 += __shfl_xor(s3, m, 64);
    }
    if (lane == 0) {
        const float4 b2v = *(const float4*)(b2g + (idx << 2));
        const float4 w3v = *(const float4*)(w3g + (idx << 2));
        float rr = b3g[idx];
        rr += lrelu(s0 + b2v.x) * w3v.x;
        rr += lrelu(s1 + b2v.y) * w3v.y;
        rr += lrelu(s2 + b2v.z) * w3v.z;
        rr += lrelu(s3 + b2v.w) * w3v.w;
        const int p = h * WW + w;
        const float ind_local = (float)inds_ws[p];
        out[p] = (ind_local + rr) * 0.0078125f;
    }
}

extern "C" void kernel_launch(void* const* d_in, const int* in_sizes, int n_in,
                              void* d_out, int out_size, void* d_ws, size_t ws_size,
                              hipStream_t stream)
{
    const float* x_in   = (const float*)d_in[0];
    const float* w_cl1  = (const float*)d_in[1];
    const float* b_cl1  = (const float*)d_in[2];
    const float* w_cl2  = (const float*)d_in[3];
    const float* b_cl2  = (const float*)d_in[4];
    const float* w_cl3  = (const float*)d_in[5];
    const float* b_cl3  = (const float*)d_in[6];
    const float* w_reg1 = (const float*)d_in[7];
    const float* b_reg1 = (const float*)d_in[8];
    const float* w2     = (const float*)d_in[9];
    const float* b2     = (const float*)d_in[10];
    const float* w3     = (const float*)d_in[11];
    const float* b3     = (const float*)d_in[12];

    float* out = (float*)d_out;
    u16* xr_ws = (u16*)d_ws;                                        // 229376*128 bf16 = 58,720,256 B
    int* inds  = (int*)((char*)d_ws + (size_t)NPIX * 128 * 2);      // + 917,504 B

    stage1_kernel<<<dim3(448 * 4), dim3(256), 0, stream>>>(
        x_in, w_cl1, b_cl1, w_cl2, b_cl2, w_cl3, b_cl3, w_reg1, b_reg1,
        xr_ws, inds, out);

    stage2_kernel<<<dim3(NPIX / 4), dim3(256), 0, stream>>>(
        xr_ws, inds, w2, b2, w3, b3, out);
}